// Round 3
// baseline (262.495 us; speedup 1.0000x reference)
//
#include <hip/hip_runtime.h>

// Decay-based linear scan: S_t = d*S_{t-1} + (1-d)*kv_t ; out_t = q_t*S_t
// fp32, (T,B,H,V,D) = (128,16,8,25,64), 204800 channels.
//
// Round-3 design: chunked parallel scan over T.
//   - T=128 split into C=8 chunks of L=16. Thread = (channel, chunk).
//   - Phase 1: local zero-init scan, all 16 states kept in registers
//     (kv loads are independent of the scan chain -> deep MLP for free).
//   - LDS Hillis-Steele (3 steps) combines chunk states: y_c = A_c + d^16 * y_{c-1}.
//   - Phase 2: S_true(j) = S_loc(j) + d^(j+1)*S_in, times q, store.
//   - 1.64M threads = 100 waves/CU queued -> Little's law satisfied by TLP,
//     kv read exactly once (registers), traffic stays at the 315 MB floor.
// Block: 512 threads = 8 waves; lane -> channel (coalesced 256B/wave/step),
// wave -> chunk. 64 channels/block share one (b,h,v) tile so h is uniform.

#define T_DIM    128
#define CH       204800
#define VD       1600          // V*D
#define C_CHUNKS 8
#define L_CHUNK  16            // T / C

__global__ __launch_bounds__(512) void sss_scan_chunked(
    const float* __restrict__ q,
    const float* __restrict__ kv,
    const float* __restrict__ decay,
    float* __restrict__ out)
{
    const int lane = threadIdx.x & 63;
    const int c    = threadIdx.x >> 6;         // chunk index 0..7 (= wave id)
    const int ch   = blockIdx.x * 64 + lane;   // channel

    const int h = (ch / VD) & 7;               // head (uniform within block)
    const float d   = decay[h * 64 + lane];    // ch & 63 == lane
    const float omd = 1.0f - d;

    const size_t base = (size_t)(c * L_CHUNK) * CH + ch;
    const float* __restrict__ kp = kv  + base;
    const float* __restrict__ qp = q   + base;
    float*       __restrict__ op = out + base;

    // Phase 1: local scan with S_in = 0; keep all L states in registers.
    float Sloc[L_CHUNK];
    float S = 0.0f;
    #pragma unroll
    for (int j = 0; j < L_CHUNK; ++j) {
        const float k = kp[j * CH];
        S = fmaf(d, S, omd * k);
        Sloc[j] = S;
    }

    // Q = d^16 (4 squarings)
    float Q = d * d;  Q *= Q;  Q *= Q;  Q *= Q;

    // Weighted inclusive scan across chunks per channel (Hillis-Steele):
    //   y_c = A_c + Q * y_{c-1}
    __shared__ float A[C_CHUNKS][64];
    A[c][lane] = S;
    float y  = S;
    float Qs = Q;
    #pragma unroll
    for (int s = 1; s < C_CHUNKS; s <<= 1) {
        __syncthreads();
        const float prev = (c >= s) ? A[c - s][lane] : 0.0f;
        __syncthreads();
        y = fmaf(Qs, prev, y);
        A[c][lane] = y;
        Qs *= Qs;
    }
    __syncthreads();
    const float Sin = (c > 0) ? A[c - 1][lane] : 0.0f;

    // Phase 2: apply incoming state + q-multiply + store.
    float r = Sin;                 // r after step j equals Sin * d^(j+1)
    #pragma unroll
    for (int j = 0; j < L_CHUNK; ++j) {
        const float qv = qp[j * CH];
        r *= d;
        const float Strue = Sloc[j] + r;
        op[j * CH] = qv * Strue;
    }
}

extern "C" void kernel_launch(void* const* d_in, const int* in_sizes, int n_in,
                              void* d_out, int out_size, void* d_ws, size_t ws_size,
                              hipStream_t stream) {
    const float* q     = (const float*)d_in[0];
    const float* kv    = (const float*)d_in[1];
    const float* decay = (const float*)d_in[2];
    float* out = (float*)d_out;

    const int threads = 512;                 // 8 waves: wave = chunk
    const int blocks  = CH / 64;             // 3200 blocks, 64 channels each
    sss_scan_chunked<<<blocks, threads, 0, stream>>>(q, kv, decay, out);
}